// Round 2
// baseline (201.979 us; speedup 1.0000x reference)
//
#include <hip/hip_runtime.h>

#define EMBED 768
#define NHEAD 12
#define HDIM 64
#define BATCH 8
#define SEQ 1024
#define ROWS (BATCH*SEQ)      // 8192
#define QKVN (3*EMBED)        // 2304
#define ATTN_SCALE 0.125f     // 1/sqrt(64)
#define QSCALE 0.18033688f    // ATTN_SCALE * log2(e), folded into Q pre-GEMM

typedef short s16x8 __attribute__((ext_vector_type(8)));
typedef short s16x4 __attribute__((ext_vector_type(4)));
typedef float f32x4 __attribute__((ext_vector_type(4)));

__device__ __forceinline__ float bf2f(unsigned short u) {
    union { unsigned int i; float f; } v; v.i = ((unsigned int)u) << 16; return v.f;
}
__device__ __forceinline__ unsigned short f2bf(float f) {
    unsigned int i = __builtin_bit_cast(unsigned int, f);
    i += 0x7FFFu + ((i >> 16) & 1u);   // RNE; finite values only
    return (unsigned short)(i >> 16);
}

// async global->LDS, 16 bytes per lane; LDS dest = wave-uniform base + lane*16
__device__ __forceinline__ void async16(short* lds, const unsigned short* g) {
    __builtin_amdgcn_global_load_lds(
        (const __attribute__((address_space(1))) unsigned int*)g,
        (__attribute__((address_space(3))) unsigned int*)lds,
        16, 0, 0);
}

__device__ __forceinline__ f32x4 mfma16(s16x4 a, s16x4 b, f32x4 c) {
#if __has_builtin(__builtin_amdgcn_mfma_f32_16x16x16bf16_1k)
    return __builtin_amdgcn_mfma_f32_16x16x16bf16_1k(a, b, c, 0, 0, 0);
#else
    asm volatile("v_mfma_f32_16x16x16_bf16 %0, %1, %2, %0" : "+v"(c) : "v"(a), "v"(b));
    return c;
#endif
}

__device__ __forceinline__ float fast_exp2(float x) {
#if __has_builtin(__builtin_amdgcn_exp2f)
    return __builtin_amdgcn_exp2f(x);
#else
    float r;
    asm("v_exp_f32 %0, %1" : "=v"(r) : "v"(x));
    return r;
#endif
}

// Fused prep.
// blk [0,432):   qkv_w fp32[768][2304] -> bf16 [2304][768]  (64x64 LDS tile transpose)
// blk [432,576): proj_w fp32[768][768] -> bf16 [768][768]
// blk [576,3648): hidden fp32 -> bf16 row-convert (8 elem/thread)
__global__ __launch_bounds__(256) void prep_k(
    const float* __restrict__ qkv_w, unsigned short* __restrict__ WqkvT,
    const float* __restrict__ proj_w, unsigned short* __restrict__ WprojT,
    const float* __restrict__ hidden, unsigned short* __restrict__ hiddenBf)
{
    __shared__ float tile[64][65];
    int blk = blockIdx.x;
    int t = threadIdx.x;
    if (blk < 576) {
        const float* in; unsigned short* outp; int K, N, tx, ty;
        if (blk < 432) { in = qkv_w; outp = WqkvT; K = EMBED; N = QKVN; tx = blk % 36; ty = blk / 36; }
        else { int b2 = blk - 432; in = proj_w; outp = WprojT; K = EMBED; N = EMBED; tx = b2 % 12; ty = b2 / 12; }
        int n0 = tx * 64, k0 = ty * 64;
        int c = t & 63, r0 = t >> 6;
        #pragma unroll
        for (int i = 0; i < 16; i++) {
            int r = r0 * 16 + i;
            tile[r][c] = in[(long long)(k0 + r) * N + n0 + c];   // coalesced 256B/row-group
        }
        __syncthreads();
        #pragma unroll
        for (int i = 0; i < 16; i++) {
            int nr = r0 * 16 + i;
            outp[(long long)(n0 + nr) * K + k0 + c] = f2bf(tile[c][nr]); // coalesced writes
        }
    } else {
        int tid = (blk - 576) * 256 + t;
        int base = tid * 8;
        float4 f0 = *(const float4*)&hidden[base];
        float4 f1 = *(const float4*)&hidden[base + 4];
        s16x8 a;
        a[0] = (short)f2bf(f0.x); a[1] = (short)f2bf(f0.y);
        a[2] = (short)f2bf(f0.z); a[3] = (short)f2bf(f0.w);
        a[4] = (short)f2bf(f1.x); a[5] = (short)f2bf(f1.y);
        a[6] = (short)f2bf(f1.z); a[7] = (short)f2bf(f1.w);
        *(s16x8*)&hiddenBf[base] = a;
    }
}

// m97-class GEMM: C[M][N] = A[M][K] @ Bt[N][K]^T + bias; A,Bt bf16; C fp32/bf16.
// tile 128x128, BK=32, 4 waves (wave: 64x64 via 4x4 mfma_16x16x32).
// LDS: unpadded 128x32 tiles, chunk-XOR swizzle on the *source* pointer
// -> global_load_lds writes AND ds_read_b128 fragment reads both conflict-free.
// SCALEQ: multiply output columns n<EMBED by QSCALE (pre-scale Q for exp2 softmax).
template <int OUT_F32, int SCALEQ>
__global__ __launch_bounds__(256) void gemm128(
    const unsigned short* __restrict__ A,
    const unsigned short* __restrict__ Bt,
    const float* __restrict__ bias,
    void* __restrict__ Cv,
    int M, int N, int K)
{
    __shared__ short As[128 * 32];
    __shared__ short Bs[128 * 32];
    int t = threadIdx.x, lane = t & 63, w = t >> 6;
    int quad = lane >> 4, low = lane & 15;
    int m0 = blockIdx.x * 128, n0 = blockIdx.y * 128;
    int wm = (w & 1) * 64, wn = (w >> 1) * 64;

    int ci0 = w * 128 + lane;
    int r0 = ci0 >> 2, c0 = (ci0 & 3) ^ ((r0 >> 1) & 3);
    int ci1 = ci0 + 64;
    int r1 = ci1 >> 2, c1 = (ci1 & 3) ^ ((r1 >> 1) & 3);
    const unsigned short* pa0 = A + (long long)(m0 + r0) * K + c0 * 8;
    const unsigned short* pa1 = A + (long long)(m0 + r1) * K + c1 * 8;
    const unsigned short* pb0 = Bt + (long long)(n0 + r0) * K + c0 * 8;
    const unsigned short* pb1 = Bt + (long long)(n0 + r1) * K + c1 * 8;
    short* la0 = As + (w * 128) * 8;
    short* la1 = As + (w * 128 + 64) * 8;
    short* lb0 = Bs + (w * 128) * 8;
    short* lb1 = Bs + (w * 128 + 64) * 8;

    f32x4 acc[4][4] = {};
    for (int k0 = 0; k0 < K; k0 += 32) {
        __syncthreads();
        async16(la0, pa0 + k0);
        async16(la1, pa1 + k0);
        async16(lb0, pb0 + k0);
        async16(lb1, pb1 + k0);
        __syncthreads();
        s16x8 af[4], bfr[4];
        #pragma unroll
        for (int i = 0; i < 4; i++) {
            int ra = wm + i * 16 + low;
            af[i] = *(const s16x8*)&As[ra * 32 + ((quad ^ ((ra >> 1) & 3)) * 8)];
            int rb = wn + i * 16 + low;
            bfr[i] = *(const s16x8*)&Bs[rb * 32 + ((quad ^ ((rb >> 1) & 3)) * 8)];
        }
        #pragma unroll
        for (int i = 0; i < 4; i++)
            #pragma unroll
            for (int j = 0; j < 4; j++)
                acc[i][j] = __builtin_amdgcn_mfma_f32_16x16x32_bf16(af[i], bfr[j], acc[i][j], 0, 0, 0);
    }
    #pragma unroll
    for (int i = 0; i < 4; i++)
        #pragma unroll
        for (int j = 0; j < 4; j++)
            #pragma unroll
            for (int r = 0; r < 4; r++) {
                int m = m0 + wm + i * 16 + quad * 4 + r;
                int n = n0 + wn + j * 16 + low;
                float v = acc[i][j][r] + bias[n];
                if (SCALEQ && n < EMBED) v *= QSCALE;
                if (OUT_F32) ((float*)Cv)[(long long)m * N + n] = v;
                else ((unsigned short*)Cv)[(long long)m * N + n] = f2bf(v);
            }
}

// MFMA flash attention v5: in-register softmax + 2-phase prefetch pipeline.
//  - S^T = mfma_16x16x32(K_frag, Q_frag): lane(quad,low) holds S[q=low][kv=n*16+quad*4+r]
//    == the A-fragment layout of mfma_16x16x16; P = exp2(S) packed via v_cvt_pk_bf16_f32
//    (Q pre-scaled by ATTN_SCALE*log2e in the QKV GEMM epilogue -> bare v_exp_f32).
//  - Double-buffered K/V tiles; per tile: issue K gload_lds + V global->reg for t+1,
//    compute tile t, ds_write V(t+1) after compute (T14 issue-early/write-late),
//    ONE barrier per tile. Hides ~200-900cyc L2/HBM latency under compute.
//  - bh = blk % 96: all 8 q-chunks of one (b,h) on one XCD; KV stays L2-resident.
__global__ __launch_bounds__(256) void attn_k(
    const unsigned short* __restrict__ mixed,  // [8192][2304] : Q|K|V per row (bf16)
    unsigned short* __restrict__ ctx)          // [8192][768]
{
    __shared__ short Ks[2][64 * 64];   // K tile [kv][d], chunk-XOR swizzled, linear rows
    __shared__ short Vt[2][64 * 68];   // V^T tile [d][kv], kv padded 64->68
    int blk = blockIdx.x;
    int bh = blk % 96;                 // XCD-grouped: 96 == 0 (mod 8)
    int qc = blk / 96;
    int b = bh / NHEAD, h = bh - b * NHEAD;
    int t = threadIdx.x;
    int lane = t & 63, w = t >> 6;
    int quad = lane >> 4, low = lane & 15;
    long long rowbase = (long long)b * SEQ;
    int q0 = qc * 128 + w * 32;
    int hoff = h * HDIM;

    // Q fragments (B-operand of swapped QK^T; pre-scaled): [qh][dhalf]
    s16x8 qf[2][2];
    #pragma unroll
    for (int qh = 0; qh < 2; qh++) {
        long long r = (rowbase + q0 + qh * 16 + low) * QKVN + hoff;
        qf[qh][0] = *(const s16x8*)&mixed[r + quad * 8];
        qf[qh][1] = *(const s16x8*)&mixed[r + 32 + quad * 8];
    }

    // K staging: slot = w*128 + lane (+64); row = slot>>3, phys chunk = slot&7.
    // LDS phys chunk c of row r holds global d-chunk (c ^ (r&7)); read applies same XOR.
    int s0 = w * 128 + lane;
    int kr0 = s0 >> 3, kc0 = s0 & 7;
    int kg = kc0 ^ (kr0 & 7);          // (kr0+8)&7 == kr0&7, so same for both slots
    const unsigned short* pk0 = mixed + (rowbase + kr0) * QKVN + EMBED + hoff + kg * 8;
    const unsigned short* pk1 = mixed + (rowbase + kr0 + 8) * QKVN + EMBED + hoff + kg * 8;

    // V staging: thread owns d = dblk*4..+3, kv rows rq*4..+3 (4x4 subtile transpose)
    int dblk = t & 15, rq = t >> 4;
    const unsigned short* pv = mixed + (rowbase + rq * 4) * QKVN + 2 * EMBED + hoff + dblk * 4;

    f32x4 o[2][4] = {};
    float lsum[2] = {0.f, 0.f};

    // prologue: stage tile 0 into buffer 0
    {
        async16(&Ks[0][(w * 128) * 8], pk0);
        async16(&Ks[0][(w * 128 + 64) * 8], pk1);
        s16x4 v0 = *(const s16x4*)&pv[0];
        s16x4 v1 = *(const s16x4*)&pv[QKVN];
        s16x4 v2 = *(const s16x4*)&pv[2 * QKVN];
        s16x4 v3 = *(const s16x4*)&pv[3 * QKVN];
        #pragma unroll
        for (int k = 0; k < 4; k++) {
            s16x4 wv;
            wv[0] = v0[k]; wv[1] = v1[k]; wv[2] = v2[k]; wv[3] = v3[k];
            *(s16x4*)&Vt[0][(dblk * 4 + k) * 68 + rq * 4] = wv;
        }
    }
    __syncthreads();

    #pragma unroll 2
    for (int it = 0; it < 16; it++) {
        int cur = it & 1;
        const short* ks = Ks[cur];
        const short* vt = Vt[cur];
        bool pf = (it + 1) < 16;
        long long koff = (long long)(it + 1) * 64 * QKVN;

        // prefetch tile it+1: K direct-to-LDS (other buffer), V to registers
        s16x4 nv0, nv1, nv2, nv3;
        if (pf) {
            async16(&Ks[cur ^ 1][(w * 128) * 8], pk0 + koff);
            async16(&Ks[cur ^ 1][(w * 128 + 64) * 8], pk1 + koff);
            nv0 = *(const s16x4*)&pv[koff];
            nv1 = *(const s16x4*)&pv[koff + QKVN];
            nv2 = *(const s16x4*)&pv[koff + 2 * QKVN];
            nv3 = *(const s16x4*)&pv[koff + 3 * QKVN];
        }

        // S^T: per kv-16 block n, sT[qh][n][r] = S[q0+qh*16+low][kv0+n*16+quad*4+r]
        f32x4 sT[2][4] = {};
        __builtin_amdgcn_s_setprio(1);
        #pragma unroll
        for (int n = 0; n < 4; n++) {
            int rr = n * 16 + low;
            int key = low & 7;
            s16x8 kf0 = *(const s16x8*)&ks[rr * 64 + ((quad ^ key) * 8)];
            s16x8 kf1 = *(const s16x8*)&ks[rr * 64 + (((quad + 4) ^ key) * 8)];
            sT[0][n] = __builtin_amdgcn_mfma_f32_16x16x32_bf16(kf0, qf[0][0], sT[0][n], 0, 0, 0);
            sT[0][n] = __builtin_amdgcn_mfma_f32_16x16x32_bf16(kf1, qf[0][1], sT[0][n], 0, 0, 0);
            sT[1][n] = __builtin_amdgcn_mfma_f32_16x16x32_bf16(kf0, qf[1][0], sT[1][n], 0, 0, 0);
            sT[1][n] = __builtin_amdgcn_mfma_f32_16x16x32_bf16(kf1, qf[1][1], sT[1][n], 0, 0, 0);
        }
        __builtin_amdgcn_s_setprio(0);

        // P = exp2(S') in-register, pack straight into x16 A-fragments
        s16x4 pfr[2][4];
        #pragma unroll
        for (int qh = 0; qh < 2; qh++)
            #pragma unroll
            for (int n = 0; n < 4; n++) {
                float e0 = fast_exp2(sT[qh][n][0]);
                float e1 = fast_exp2(sT[qh][n][1]);
                float e2 = fast_exp2(sT[qh][n][2]);
                float e3 = fast_exp2(sT[qh][n][3]);
                lsum[qh] += (e0 + e1) + (e2 + e3);
                unsigned int w0, w1;
                asm("v_cvt_pk_bf16_f32 %0, %1, %2" : "=v"(w0) : "v"(e0), "v"(e1));
                asm("v_cvt_pk_bf16_f32 %0, %1, %2" : "=v"(w1) : "v"(e2), "v"(e3));
                union { unsigned int u[2]; s16x4 v; } pu;
                pu.u[0] = w0; pu.u[1] = w1;
                pfr[qh][n] = pu.v;
            }

        // O += P @ V  (x16 MFMAs; V frag = contiguous b64 from V^T)
        __builtin_amdgcn_s_setprio(1);
        #pragma unroll
        for (int nt = 0; nt < 4; nt++) {
            int drow = nt * 16 + low;
            #pragma unroll
            for (int n = 0; n < 4; n++) {
                s16x4 vf = *(const s16x4*)&vt[drow * 68 + n * 16 + quad * 4];
                o[0][nt] = mfma16(pfr[0][n], vf, o[0][nt]);
                o[1][nt] = mfma16(pfr[1][n], vf, o[1][nt]);
            }
        }
        __builtin_amdgcn_s_setprio(0);

        // late V write for tile it+1 (HBM latency hidden under compute above)
        if (pf) {
            #pragma unroll
            for (int k = 0; k < 4; k++) {
                s16x4 wv;
                wv[0] = nv0[k]; wv[1] = nv1[k]; wv[2] = nv2[k]; wv[3] = nv3[k];
                *(s16x4*)&Vt[cur ^ 1][(dblk * 4 + k) * 68 + rq * 4] = wv;
            }
        }
        __syncthreads();   // drains vmcnt/lgkm: K+V of it+1 staged, all reads of cur done
    }

    // full row-sums: combine the 4 quad-partials for each q=low
    #pragma unroll
    for (int qh = 0; qh < 2; qh++) {
        lsum[qh] += __shfl_xor(lsum[qh], 16, 64);
        lsum[qh] += __shfl_xor(lsum[qh], 32, 64);
    }
    #pragma unroll
    for (int qh = 0; qh < 2; qh++)
        #pragma unroll
        for (int r = 0; r < 4; r++) {
            float inv = 1.0f / __shfl(lsum[qh], quad * 4 + r, 64);
            int q = q0 + qh * 16 + quad * 4 + r;
            #pragma unroll
            for (int nt = 0; nt < 4; nt++)
                ctx[(rowbase + q) * EMBED + hoff + nt * 16 + low] =
                    f2bf(o[qh][nt][r] * inv);
        }
}

extern "C" void kernel_launch(void* const* d_in, const int* in_sizes, int n_in,
                              void* d_out, int out_size, void* d_ws, size_t ws_size,
                              hipStream_t stream) {
    const float* hidden = (const float*)d_in[0];
    const float* qkv_w  = (const float*)d_in[1];
    const float* qkv_b  = (const float*)d_in[2];
    const float* proj_w = (const float*)d_in[3];
    const float* proj_b = (const float*)d_in[4];
    float* out = (float*)d_out;        // fp32 output

    char* ws = (char*)d_ws;
    // hiddenBf dead after QKV GEMM; ctx written only by attn -> alias (stream-serialized).
    unsigned short* hiddenBf = (unsigned short*)ws;                      // 8192x768  bf16
    unsigned short* ctx      = (unsigned short*)ws;                      // aliases hiddenBf
    unsigned short* WqkvT    = (unsigned short*)(ws + 12582912);         // 2304x768  bf16
    unsigned short* WprojT   = (unsigned short*)(ws + 16121856);         // 768x768   bf16
    unsigned short* mixed    = (unsigned short*)(ws + 17301504);         // 8192x2304 bf16

    prep_k<<<dim3(3648), 256, 0, stream>>>(qkv_w, WqkvT, proj_w, WprojT, hidden, hiddenBf);
    gemm128<0, 1><<<dim3(ROWS / 128, QKVN / 128), 256, 0, stream>>>(
        hiddenBf, WqkvT, qkv_b, mixed, ROWS, QKVN, EMBED);
    attn_k<<<dim3(96 * 8), 256, 0, stream>>>(mixed, ctx);
    gemm128<1, 0><<<dim3(ROWS / 128, EMBED / 128), 256, 0, stream>>>(
        ctx, WprojT, proj_b, out, ROWS, EMBED, EMBED);
}

// Round 7
// 198.713 us; speedup vs baseline: 1.0164x; 1.0164x over previous
//
#include <hip/hip_runtime.h>

#define EMBED 768
#define NHEAD 12
#define HDIM 64
#define BATCH 8
#define SEQ 1024
#define ROWS (BATCH*SEQ)      // 8192
#define QKVN (3*EMBED)        // 2304
#define ATTN_SCALE 0.125f     // 1/sqrt(64)

typedef short s16x8 __attribute__((ext_vector_type(8)));
typedef short s16x4 __attribute__((ext_vector_type(4)));
typedef float f32x4 __attribute__((ext_vector_type(4)));

__device__ __forceinline__ float bf2f(unsigned short u) {
    union { unsigned int i; float f; } v; v.i = ((unsigned int)u) << 16; return v.f;
}
__device__ __forceinline__ unsigned short f2bf(float f) {
    unsigned int i = __builtin_bit_cast(unsigned int, f);
    i += 0x7FFFu + ((i >> 16) & 1u);   // RNE; finite values only
    return (unsigned short)(i >> 16);
}

// async global->LDS, 16 bytes per lane; LDS dest = wave-uniform base + lane*16
__device__ __forceinline__ void async16(short* lds, const unsigned short* g) {
    __builtin_amdgcn_global_load_lds(
        (const __attribute__((address_space(1))) unsigned int*)g,
        (__attribute__((address_space(3))) unsigned int*)lds,
        16, 0, 0);
}

__device__ __forceinline__ f32x4 mfma16(s16x4 a, s16x4 b, f32x4 c) {
#if __has_builtin(__builtin_amdgcn_mfma_f32_16x16x16bf16_1k)
    return __builtin_amdgcn_mfma_f32_16x16x16bf16_1k(a, b, c, 0, 0, 0);
#else
    asm volatile("v_mfma_f32_16x16x16_bf16 %0, %1, %2, %0" : "+v"(c) : "v"(a), "v"(b));
    return c;
#endif
}

// Fused prep.
// blk [0,432):   qkv_w fp32[768][2304] -> bf16 [2304][768]  (64x64 LDS tile transpose)
// blk [432,576): proj_w fp32[768][768] -> bf16 [768][768]
// blk [576,3648): hidden fp32 -> bf16 row-convert (8 elem/thread)
__global__ __launch_bounds__(256) void prep_k(
    const float* __restrict__ qkv_w, unsigned short* __restrict__ WqkvT,
    const float* __restrict__ proj_w, unsigned short* __restrict__ WprojT,
    const float* __restrict__ hidden, unsigned short* __restrict__ hiddenBf)
{
    __shared__ float tile[64][65];
    int blk = blockIdx.x;
    int t = threadIdx.x;
    if (blk < 576) {
        const float* in; unsigned short* outp; int K, N, tx, ty;
        if (blk < 432) { in = qkv_w; outp = WqkvT; K = EMBED; N = QKVN; tx = blk % 36; ty = blk / 36; }
        else { int b2 = blk - 432; in = proj_w; outp = WprojT; K = EMBED; N = EMBED; tx = b2 % 12; ty = b2 / 12; }
        int n0 = tx * 64, k0 = ty * 64;
        int c = t & 63, r0 = t >> 6;
        #pragma unroll
        for (int i = 0; i < 16; i++) {
            int r = r0 * 16 + i;
            tile[r][c] = in[(long long)(k0 + r) * N + n0 + c];   // coalesced 256B/row-group
        }
        __syncthreads();
        #pragma unroll
        for (int i = 0; i < 16; i++) {
            int nr = r0 * 16 + i;
            outp[(long long)(n0 + nr) * K + k0 + c] = f2bf(tile[c][nr]); // coalesced writes
        }
    } else {
        int tid = (blk - 576) * 256 + t;
        int base = tid * 8;
        float4 f0 = *(const float4*)&hidden[base];
        float4 f1 = *(const float4*)&hidden[base + 4];
        s16x8 a;
        a[0] = (short)f2bf(f0.x); a[1] = (short)f2bf(f0.y);
        a[2] = (short)f2bf(f0.z); a[3] = (short)f2bf(f0.w);
        a[4] = (short)f2bf(f1.x); a[5] = (short)f2bf(f1.y);
        a[6] = (short)f2bf(f1.z); a[7] = (short)f2bf(f1.w);
        *(s16x8*)&hiddenBf[base] = a;
    }
}

// m97-class GEMM (PROVEN round-1 structure): C[M][N] = A[M][K] @ Bt[N][K]^T + bias.
// tile 128x128, BK=32, 4 waves (wave: 64x64 via 4x4 mfma_16x16x32).
// LDS: unpadded 128x32 tiles, chunk-XOR swizzle on the *source* pointer
// -> global_load_lds writes AND ds_read_b128 fragment reads both conflict-free.
// NEW (round 7): XCD-aware slab swizzle of block indices ONLY (pure bijection,
// no memory/sync change). Each XCD (orig%8, round-robin dispatch) owns an
// 8-m-tile slab (A slab 1.57MB -> L2-resident across all n-tiles).
// Requires gridDim.x == 64 (true for both calls: M=8192).
template <int OUT_F32>
__global__ __launch_bounds__(256) void gemm128(
    const unsigned short* __restrict__ A,
    const unsigned short* __restrict__ Bt,
    const float* __restrict__ bias,
    void* __restrict__ Cv,
    int M, int N, int K)
{
    __shared__ short As[128 * 32];
    __shared__ short Bs[128 * 32];
    int t = threadIdx.x, lane = t & 63, w = t >> 6;
    int quad = lane >> 4, low = lane & 15;
    // orig = (local<<3)|xcd ; (bx,by) = (xcd*8+(local&7), local>>3) — bijective.
    int orig = blockIdx.y * gridDim.x + blockIdx.x;
    int xcd = orig & 7;
    int local = orig >> 3;
    int bx = xcd * 8 + (local & 7);
    int by = local >> 3;
    int m0 = bx * 128, n0 = by * 128;
    int wm = (w & 1) * 64, wn = (w >> 1) * 64;

    int ci0 = w * 128 + lane;
    int r0 = ci0 >> 2, c0 = (ci0 & 3) ^ ((r0 >> 1) & 3);
    int ci1 = ci0 + 64;
    int r1 = ci1 >> 2, c1 = (ci1 & 3) ^ ((r1 >> 1) & 3);
    const unsigned short* pa0 = A + (long long)(m0 + r0) * K + c0 * 8;
    const unsigned short* pa1 = A + (long long)(m0 + r1) * K + c1 * 8;
    const unsigned short* pb0 = Bt + (long long)(n0 + r0) * K + c0 * 8;
    const unsigned short* pb1 = Bt + (long long)(n0 + r1) * K + c1 * 8;
    short* la0 = As + (w * 128) * 8;
    short* la1 = As + (w * 128 + 64) * 8;
    short* lb0 = Bs + (w * 128) * 8;
    short* lb1 = Bs + (w * 128 + 64) * 8;

    f32x4 acc[4][4] = {};
    for (int k0 = 0; k0 < K; k0 += 32) {
        __syncthreads();
        async16(la0, pa0 + k0);
        async16(la1, pa1 + k0);
        async16(lb0, pb0 + k0);
        async16(lb1, pb1 + k0);
        __syncthreads();
        s16x8 af[4], bfr[4];
        #pragma unroll
        for (int i = 0; i < 4; i++) {
            int ra = wm + i * 16 + low;
            af[i] = *(const s16x8*)&As[ra * 32 + ((quad ^ ((ra >> 1) & 3)) * 8)];
            int rb = wn + i * 16 + low;
            bfr[i] = *(const s16x8*)&Bs[rb * 32 + ((quad ^ ((rb >> 1) & 3)) * 8)];
        }
        #pragma unroll
        for (int i = 0; i < 4; i++)
            #pragma unroll
            for (int j = 0; j < 4; j++)
                acc[i][j] = __builtin_amdgcn_mfma_f32_16x16x32_bf16(af[i], bfr[j], acc[i][j], 0, 0, 0);
    }
    #pragma unroll
    for (int i = 0; i < 4; i++)
        #pragma unroll
        for (int j = 0; j < 4; j++)
            #pragma unroll
            for (int r = 0; r < 4; r++) {
                int m = m0 + wm + i * 16 + quad * 4 + r;
                int n = n0 + wn + j * 16 + low;
                float v = acc[i][j][r] + bias[n];
                if (OUT_F32) ((float*)Cv)[(long long)m * N + n] = v;
                else ((unsigned short*)Cv)[(long long)m * N + n] = f2bf(v);
            }
}

// MFMA flash attention v4 (BYTE-EXACT round-1 PROVEN kernel, 52.4us):
//  - S^T = mfma_16x16x32(K_frag, Q_frag): lane(quad,low) holds S[q=low][kv=n*16+quad*4+r]
//    == exactly the A-fragment layout of mfma_16x16x16 (row=low, k=quad*4+i).
//  - P = exp(S*scale) packed in-register via v_cvt_pk_bf16_f32 -> PV uses K=16 MFMAs.
//    P never touches LDS; row-sum is a per-lane scalar.
//  - K staged via global_load_lds with chunk-XOR pre-swizzled source (conflict-free b128 reads).
//  - V^T staged as 4x4 lane-local subtiles -> 4x ds_write_b64/thread, stride 68 (bank floor).
//  - bh = blk % 96: all 8 q-chunks of one (b,h) on one XCD; 12 heads x 256KB KV fits its L2.
__global__ __launch_bounds__(256) void attn_k(
    const unsigned short* __restrict__ mixed,  // [8192][2304] : Q|K|V per row (bf16)
    unsigned short* __restrict__ ctx)          // [8192][768]
{
    __shared__ short Ks[64 * 64];      // K tile [kv][d], chunk-XOR swizzled, linear rows
    __shared__ short Vt[64 * 68];      // V^T tile [d][kv], kv padded 64->68
    int blk = blockIdx.x;
    int bh = blk % 96;                 // XCD-grouped: 96 == 0 (mod 8)
    int qc = blk / 96;
    int b = bh / NHEAD, h = bh - b * NHEAD;
    int t = threadIdx.x;
    int lane = t & 63, w = t >> 6;
    int quad = lane >> 4, low = lane & 15;
    long long rowbase = (long long)b * SEQ;
    int q0 = qc * 128 + w * 32;
    int hoff = h * HDIM;

    // Q fragments (B-operand of swapped QK^T; layout identical to A-frag): [qh][dhalf]
    s16x8 qf[2][2];
    #pragma unroll
    for (int qh = 0; qh < 2; qh++) {
        long long r = (rowbase + q0 + qh * 16 + low) * QKVN + hoff;
        qf[qh][0] = *(const s16x8*)&mixed[r + quad * 8];
        qf[qh][1] = *(const s16x8*)&mixed[r + 32 + quad * 8];
    }

    // K staging: slot = w*128 + lane (+64); row = slot>>3, phys chunk = slot&7.
    // LDS phys chunk c of row r holds global d-chunk (c ^ (r&7)); read applies same XOR.
    int s0 = w * 128 + lane;
    int kr0 = s0 >> 3, kc0 = s0 & 7;
    int kg = kc0 ^ (kr0 & 7);          // (kr0+8)&7 == kr0&7, so same for both slots
    const unsigned short* pk0 = mixed + (rowbase + kr0) * QKVN + EMBED + hoff + kg * 8;
    const unsigned short* pk1 = mixed + (rowbase + kr0 + 8) * QKVN + EMBED + hoff + kg * 8;
    short* lk0 = Ks + (w * 128) * 8;
    short* lk1 = Ks + (w * 128 + 64) * 8;

    // V staging: thread owns d = dblk*4..+3, kv rows rq*4..+3 (4x4 subtile transpose)
    int dblk = t & 15, rq = t >> 4;
    const unsigned short* pv = mixed + (rowbase + rq * 4) * QKVN + 2 * EMBED + hoff + dblk * 4;

    f32x4 o[2][4] = {};
    float lsum[2] = {0.f, 0.f};

    for (int kv0 = 0; kv0 < SEQ; kv0 += 64) {
        long long koff = (long long)kv0 * QKVN;
        __syncthreads();
        async16(lk0, pk0 + koff);
        async16(lk1, pk1 + koff);
        s16x4 v0 = *(const s16x4*)&pv[koff];
        s16x4 v1 = *(const s16x4*)&pv[koff + QKVN];
        s16x4 v2 = *(const s16x4*)&pv[koff + 2 * QKVN];
        s16x4 v3 = *(const s16x4*)&pv[koff + 3 * QKVN];
        #pragma unroll
        for (int k = 0; k < 4; k++) {
            s16x4 wv;
            wv[0] = v0[k]; wv[1] = v1[k]; wv[2] = v2[k]; wv[3] = v3[k];
            *(s16x4*)&Vt[(dblk * 4 + k) * 68 + rq * 4] = wv;
        }
        __syncthreads();

        // S^T: per kv-16 block n, sT[qh][n][r] = S[q0+qh*16+low][kv0+n*16+quad*4+r]
        f32x4 sT[2][4] = {};
        __builtin_amdgcn_s_setprio(1);
        #pragma unroll
        for (int n = 0; n < 4; n++) {
            int rr = n * 16 + low;
            int key = low & 7;
            s16x8 kf0 = *(const s16x8*)&Ks[rr * 64 + ((quad ^ key) * 8)];
            s16x8 kf1 = *(const s16x8*)&Ks[rr * 64 + (((quad + 4) ^ key) * 8)];
            sT[0][n] = __builtin_amdgcn_mfma_f32_16x16x32_bf16(kf0, qf[0][0], sT[0][n], 0, 0, 0);
            sT[0][n] = __builtin_amdgcn_mfma_f32_16x16x32_bf16(kf1, qf[0][1], sT[0][n], 0, 0, 0);
            sT[1][n] = __builtin_amdgcn_mfma_f32_16x16x32_bf16(kf0, qf[1][0], sT[1][n], 0, 0, 0);
            sT[1][n] = __builtin_amdgcn_mfma_f32_16x16x32_bf16(kf1, qf[1][1], sT[1][n], 0, 0, 0);
        }
        __builtin_amdgcn_s_setprio(0);

        // P = exp(S*scale): in-register, pack straight into x16 A-fragments
        s16x4 pf[2][4];
        #pragma unroll
        for (int qh = 0; qh < 2; qh++)
            #pragma unroll
            for (int n = 0; n < 4; n++) {
                float e0 = __expf(sT[qh][n][0] * ATTN_SCALE);
                float e1 = __expf(sT[qh][n][1] * ATTN_SCALE);
                float e2 = __expf(sT[qh][n][2] * ATTN_SCALE);
                float e3 = __expf(sT[qh][n][3] * ATTN_SCALE);
                lsum[qh] += (e0 + e1) + (e2 + e3);
                unsigned int w0, w1;
                asm("v_cvt_pk_bf16_f32 %0, %1, %2" : "=v"(w0) : "v"(e0), "v"(e1));
                asm("v_cvt_pk_bf16_f32 %0, %1, %2" : "=v"(w1) : "v"(e2), "v"(e3));
                union { unsigned int u[2]; s16x4 v; } pu;
                pu.u[0] = w0; pu.u[1] = w1;
                pf[qh][n] = pu.v;
            }

        // O += P @ V  (x16 MFMAs; V frag = contiguous b64 from V^T)
        __builtin_amdgcn_s_setprio(1);
        #pragma unroll
        for (int nt = 0; nt < 4; nt++) {
            int drow = nt * 16 + low;
            #pragma unroll
            for (int n = 0; n < 4; n++) {
                s16x4 vf = *(const s16x4*)&Vt[drow * 68 + n * 16 + quad * 4];
                o[0][nt] = mfma16(pf[0][n], vf, o[0][nt]);
                o[1][nt] = mfma16(pf[1][n], vf, o[1][nt]);
            }
        }
        __builtin_amdgcn_s_setprio(0);
    }

    // full row-sums: combine the 4 quad-partials for each q=low
    #pragma unroll
    for (int qh = 0; qh < 2; qh++) {
        lsum[qh] += __shfl_xor(lsum[qh], 16, 64);
        lsum[qh] += __shfl_xor(lsum[qh], 32, 64);
    }
    #pragma unroll
    for (int qh = 0; qh < 2; qh++)
        #pragma unroll
        for (int r = 0; r < 4; r++) {
            float inv = 1.0f / __shfl(lsum[qh], quad * 4 + r, 64);
            int q = q0 + qh * 16 + quad * 4 + r;
            #pragma unroll
            for (int nt = 0; nt < 4; nt++)
                ctx[(rowbase + q) * EMBED + hoff + nt * 16 + low] =
                    f2bf(o[qh][nt][r] * inv);
        }
}

extern "C" void kernel_launch(void* const* d_in, const int* in_sizes, int n_in,
                              void* d_out, int out_size, void* d_ws, size_t ws_size,
                              hipStream_t stream) {
    const float* hidden = (const float*)d_in[0];
    const float* qkv_w  = (const float*)d_in[1];
    const float* qkv_b  = (const float*)d_in[2];
    const float* proj_w = (const float*)d_in[3];
    const float* proj_b = (const float*)d_in[4];
    float* out = (float*)d_out;        // fp32 output

    char* ws = (char*)d_ws;
    // hiddenBf dead after QKV GEMM; ctx written only by attn -> alias (stream-serialized).
    unsigned short* hiddenBf = (unsigned short*)ws;                      // 8192x768  bf16
    unsigned short* ctx      = (unsigned short*)ws;                      // aliases hiddenBf
    unsigned short* WqkvT    = (unsigned short*)(ws + 12582912);         // 2304x768  bf16
    unsigned short* WprojT   = (unsigned short*)(ws + 16121856);         // 768x768   bf16
    unsigned short* mixed    = (unsigned short*)(ws + 17301504);         // 8192x2304 bf16

    prep_k<<<dim3(3648), 256, 0, stream>>>(qkv_w, WqkvT, proj_w, WprojT, hidden, hiddenBf);
    gemm128<0><<<dim3(ROWS / 128, QKVN / 128), 256, 0, stream>>>(
        hiddenBf, WqkvT, qkv_b, mixed, ROWS, QKVN, EMBED);
    attn_k<<<dim3(96 * 8), 256, 0, stream>>>(mixed, ctx);
    gemm128<1><<<dim3(ROWS / 128, EMBED / 128), 256, 0, stream>>>(
        ctx, WprojT, proj_b, out, ROWS, EMBED, EMBED);
}

// Round 9
// 192.238 us; speedup vs baseline: 1.0507x; 1.0337x over previous
//
#include <hip/hip_runtime.h>

#define EMBED 768
#define NHEAD 12
#define HDIM 64
#define BATCH 8
#define SEQ 1024
#define ROWS (BATCH*SEQ)      // 8192
#define QKVN (3*EMBED)        // 2304
#define ATTN_SCALE 0.125f     // 1/sqrt(64)

typedef short s16x8 __attribute__((ext_vector_type(8)));
typedef short s16x4 __attribute__((ext_vector_type(4)));
typedef float f32x4 __attribute__((ext_vector_type(4)));

__device__ __forceinline__ float bf2f(unsigned short u) {
    union { unsigned int i; float f; } v; v.i = ((unsigned int)u) << 16; return v.f;
}
__device__ __forceinline__ unsigned short f2bf(float f) {
    unsigned int i = __builtin_bit_cast(unsigned int, f);
    i += 0x7FFFu + ((i >> 16) & 1u);   // RNE; finite values only
    return (unsigned short)(i >> 16);
}

// async global->LDS, 16 bytes per lane; LDS dest = wave-uniform base + lane*16
__device__ __forceinline__ void async16(short* lds, const unsigned short* g) {
    __builtin_amdgcn_global_load_lds(
        (const __attribute__((address_space(1))) unsigned int*)g,
        (__attribute__((address_space(3))) unsigned int*)lds,
        16, 0, 0);
}

__device__ __forceinline__ f32x4 mfma16(s16x4 a, s16x4 b, f32x4 c) {
#if __has_builtin(__builtin_amdgcn_mfma_f32_16x16x16bf16_1k)
    return __builtin_amdgcn_mfma_f32_16x16x16bf16_1k(a, b, c, 0, 0, 0);
#else
    asm volatile("v_mfma_f32_16x16x16_bf16 %0, %1, %2, %0" : "+v"(c) : "v"(a), "v"(b));
    return c;
#endif
}

// Fused prep.
// blk [0,432):   qkv_w fp32[768][2304] -> bf16 [2304][768]  (64x64 LDS tile transpose)
// blk [432,576): proj_w fp32[768][768] -> bf16 [768][768]
// blk [576,3648): hidden fp32 -> bf16 row-convert (8 elem/thread)
__global__ __launch_bounds__(256) void prep_k(
    const float* __restrict__ qkv_w, unsigned short* __restrict__ WqkvT,
    const float* __restrict__ proj_w, unsigned short* __restrict__ WprojT,
    const float* __restrict__ hidden, unsigned short* __restrict__ hiddenBf)
{
    __shared__ float tile[64][65];
    int blk = blockIdx.x;
    int t = threadIdx.x;
    if (blk < 576) {
        const float* in; unsigned short* outp; int K, N, tx, ty;
        if (blk < 432) { in = qkv_w; outp = WqkvT; K = EMBED; N = QKVN; tx = blk % 36; ty = blk / 36; }
        else { int b2 = blk - 432; in = proj_w; outp = WprojT; K = EMBED; N = EMBED; tx = b2 % 12; ty = b2 / 12; }
        int n0 = tx * 64, k0 = ty * 64;
        int c = t & 63, r0 = t >> 6;
        #pragma unroll
        for (int i = 0; i < 16; i++) {
            int r = r0 * 16 + i;
            tile[r][c] = in[(long long)(k0 + r) * N + n0 + c];   // coalesced 256B/row-group
        }
        __syncthreads();
        #pragma unroll
        for (int i = 0; i < 16; i++) {
            int nr = r0 * 16 + i;
            outp[(long long)(n0 + nr) * K + k0 + c] = f2bf(tile[c][nr]); // coalesced writes
        }
    } else {
        int tid = (blk - 576) * 256 + t;
        int base = tid * 8;
        float4 f0 = *(const float4*)&hidden[base];
        float4 f1 = *(const float4*)&hidden[base + 4];
        s16x8 a;
        a[0] = (short)f2bf(f0.x); a[1] = (short)f2bf(f0.y);
        a[2] = (short)f2bf(f0.z); a[3] = (short)f2bf(f0.w);
        a[4] = (short)f2bf(f1.x); a[5] = (short)f2bf(f1.y);
        a[6] = (short)f2bf(f1.z); a[7] = (short)f2bf(f1.w);
        *(s16x8*)&hiddenBf[base] = a;
    }
}

// m97-class GEMM + 2-phase double-buffer (T3-minimum): C = A @ Bt^T + bias.
// tile 128x128, BK=32, 4 waves (wave: 64x64 via 4x4 mfma_16x16x32).
// LDS: unpadded 128x32 tiles x2 buffers, chunk-XOR swizzle on the *source* pointer
// -> global_load_lds writes AND ds_read_b128 fragment reads both conflict-free.
// Per K-step: STAGE(next -> other buffer) BEFORE ds_read+MFMA(cur), ONE barrier.
// Sync audit: __syncthreads drains vmcnt(0)+lgkmcnt(0) per wave, so (a) each
// wave's reads of cur are in VGPRs before it signals, (b) re-stage of cur in
// iter i+1 is strictly after that barrier, (c) stage of nxt has landed for all
// waves at barrier exit. Loads get the full MFMA phase to cover L2 latency.
// XCD slab swizzle (round-7 proven): each XCD owns an 8-m-tile slab.
template <int OUT_F32>
__global__ __launch_bounds__(256) void gemm128(
    const unsigned short* __restrict__ A,
    const unsigned short* __restrict__ Bt,
    const float* __restrict__ bias,
    void* __restrict__ Cv,
    int M, int N, int K)
{
    __shared__ short As[2][128 * 32];
    __shared__ short Bs[2][128 * 32];
    int t = threadIdx.x, lane = t & 63, w = t >> 6;
    int quad = lane >> 4, low = lane & 15;
    // orig = (local<<3)|xcd ; (bx,by) = (xcd*8+(local&7), local>>3) — bijective.
    int orig = blockIdx.y * gridDim.x + blockIdx.x;
    int xcd = orig & 7;
    int local = orig >> 3;
    int bx = xcd * 8 + (local & 7);
    int by = local >> 3;
    int m0 = bx * 128, n0 = by * 128;
    int wm = (w & 1) * 64, wn = (w >> 1) * 64;

    int ci0 = w * 128 + lane;
    int r0 = ci0 >> 2, c0 = (ci0 & 3) ^ ((r0 >> 1) & 3);
    int ci1 = ci0 + 64;
    int r1 = ci1 >> 2, c1 = (ci1 & 3) ^ ((r1 >> 1) & 3);
    const unsigned short* pa0 = A + (long long)(m0 + r0) * K + c0 * 8;
    const unsigned short* pa1 = A + (long long)(m0 + r1) * K + c1 * 8;
    const unsigned short* pb0 = Bt + (long long)(n0 + r0) * K + c0 * 8;
    const unsigned short* pb1 = Bt + (long long)(n0 + r1) * K + c1 * 8;
    int lo0 = (w * 128) * 8;        // this wave's first chunk group (short offset)
    int lo1 = (w * 128 + 64) * 8;   // second chunk group

    // prologue: stage K-step 0 into buffer 0
    async16(&As[0][lo0], pa0);
    async16(&As[0][lo1], pa1);
    async16(&Bs[0][lo0], pb0);
    async16(&Bs[0][lo1], pb1);
    __syncthreads();

    f32x4 acc[4][4] = {};
    int cur = 0;
    for (int k0 = 0; k0 < K; k0 += 32) {
        int nxt = cur ^ 1;
        // stage next K-step into the other buffer (issued before compute;
        // lands by the barrier below, latency hidden under ds_read+MFMA)
        if (k0 + 32 < K) {
            async16(&As[nxt][lo0], pa0 + k0 + 32);
            async16(&As[nxt][lo1], pa1 + k0 + 32);
            async16(&Bs[nxt][lo0], pb0 + k0 + 32);
            async16(&Bs[nxt][lo1], pb1 + k0 + 32);
        }
        const short* as = As[cur];
        const short* bs = Bs[cur];
        s16x8 af[4], bfr[4];
        #pragma unroll
        for (int i = 0; i < 4; i++) {
            int ra = wm + i * 16 + low;
            af[i] = *(const s16x8*)&as[ra * 32 + ((quad ^ ((ra >> 1) & 3)) * 8)];
            int rb = wn + i * 16 + low;
            bfr[i] = *(const s16x8*)&bs[rb * 32 + ((quad ^ ((rb >> 1) & 3)) * 8)];
        }
        #pragma unroll
        for (int i = 0; i < 4; i++)
            #pragma unroll
            for (int j = 0; j < 4; j++)
                acc[i][j] = __builtin_amdgcn_mfma_f32_16x16x32_bf16(af[i], bfr[j], acc[i][j], 0, 0, 0);
        __syncthreads();   // reads of cur done (lgkm), stage of nxt landed (vmcnt)
        cur = nxt;
    }
    #pragma unroll
    for (int i = 0; i < 4; i++)
        #pragma unroll
        for (int j = 0; j < 4; j++)
            #pragma unroll
            for (int r = 0; r < 4; r++) {
                int m = m0 + wm + i * 16 + quad * 4 + r;
                int n = n0 + wn + j * 16 + low;
                float v = acc[i][j][r] + bias[n];
                if (OUT_F32) ((float*)Cv)[(long long)m * N + n] = v;
                else ((unsigned short*)Cv)[(long long)m * N + n] = f2bf(v);
            }
}

// MFMA flash attention v4 (BYTE-EXACT round-1/round-7 PROVEN kernel, 52.4us):
//  - S^T = mfma_16x16x32(K_frag, Q_frag): lane(quad,low) holds S[q=low][kv=n*16+quad*4+r]
//    == exactly the A-fragment layout of mfma_16x16x16 (row=low, k=quad*4+i).
//  - P = exp(S*scale) packed in-register via v_cvt_pk_bf16_f32 -> PV uses K=16 MFMAs.
//    P never touches LDS; row-sum is a per-lane scalar.
//  - K staged via global_load_lds with chunk-XOR pre-swizzled source (conflict-free b128 reads).
//  - V^T staged as 4x4 lane-local subtiles -> 4x ds_write_b64/thread, stride 68 (bank floor).
//  - bh = blk % 96: all 8 q-chunks of one (b,h) on one XCD; 12 heads x 256KB KV fits its L2.
__global__ __launch_bounds__(256) void attn_k(
    const unsigned short* __restrict__ mixed,  // [8192][2304] : Q|K|V per row (bf16)
    unsigned short* __restrict__ ctx)          // [8192][768]
{
    __shared__ short Ks[64 * 64];      // K tile [kv][d], chunk-XOR swizzled, linear rows
    __shared__ short Vt[64 * 68];      // V^T tile [d][kv], kv padded 64->68
    int blk = blockIdx.x;
    int bh = blk % 96;                 // XCD-grouped: 96 == 0 (mod 8)
    int qc = blk / 96;
    int b = bh / NHEAD, h = bh - b * NHEAD;
    int t = threadIdx.x;
    int lane = t & 63, w = t >> 6;
    int quad = lane >> 4, low = lane & 15;
    long long rowbase = (long long)b * SEQ;
    int q0 = qc * 128 + w * 32;
    int hoff = h * HDIM;

    // Q fragments (B-operand of swapped QK^T; layout identical to A-frag): [qh][dhalf]
    s16x8 qf[2][2];
    #pragma unroll
    for (int qh = 0; qh < 2; qh++) {
        long long r = (rowbase + q0 + qh * 16 + low) * QKVN + hoff;
        qf[qh][0] = *(const s16x8*)&mixed[r + quad * 8];
        qf[qh][1] = *(const s16x8*)&mixed[r + 32 + quad * 8];
    }

    // K staging: slot = w*128 + lane (+64); row = slot>>3, phys chunk = slot&7.
    // LDS phys chunk c of row r holds global d-chunk (c ^ (r&7)); read applies same XOR.
    int s0 = w * 128 + lane;
    int kr0 = s0 >> 3, kc0 = s0 & 7;
    int kg = kc0 ^ (kr0 & 7);          // (kr0+8)&7 == kr0&7, so same for both slots
    const unsigned short* pk0 = mixed + (rowbase + kr0) * QKVN + EMBED + hoff + kg * 8;
    const unsigned short* pk1 = mixed + (rowbase + kr0 + 8) * QKVN + EMBED + hoff + kg * 8;
    short* lk0 = Ks + (w * 128) * 8;
    short* lk1 = Ks + (w * 128 + 64) * 8;

    // V staging: thread owns d = dblk*4..+3, kv rows rq*4..+3 (4x4 subtile transpose)
    int dblk = t & 15, rq = t >> 4;
    const unsigned short* pv = mixed + (rowbase + rq * 4) * QKVN + 2 * EMBED + hoff + dblk * 4;

    f32x4 o[2][4] = {};
    float lsum[2] = {0.f, 0.f};

    for (int kv0 = 0; kv0 < SEQ; kv0 += 64) {
        long long koff = (long long)kv0 * QKVN;
        __syncthreads();
        async16(lk0, pk0 + koff);
        async16(lk1, pk1 + koff);
        s16x4 v0 = *(const s16x4*)&pv[koff];
        s16x4 v1 = *(const s16x4*)&pv[koff + QKVN];
        s16x4 v2 = *(const s16x4*)&pv[koff + 2 * QKVN];
        s16x4 v3 = *(const s16x4*)&pv[koff + 3 * QKVN];
        #pragma unroll
        for (int k = 0; k < 4; k++) {
            s16x4 wv;
            wv[0] = v0[k]; wv[1] = v1[k]; wv[2] = v2[k]; wv[3] = v3[k];
            *(s16x4*)&Vt[(dblk * 4 + k) * 68 + rq * 4] = wv;
        }
        __syncthreads();

        // S^T: per kv-16 block n, sT[qh][n][r] = S[q0+qh*16+low][kv0+n*16+quad*4+r]
        f32x4 sT[2][4] = {};
        __builtin_amdgcn_s_setprio(1);
        #pragma unroll
        for (int n = 0; n < 4; n++) {
            int rr = n * 16 + low;
            int key = low & 7;
            s16x8 kf0 = *(const s16x8*)&Ks[rr * 64 + ((quad ^ key) * 8)];
            s16x8 kf1 = *(const s16x8*)&Ks[rr * 64 + (((quad + 4) ^ key) * 8)];
            sT[0][n] = __builtin_amdgcn_mfma_f32_16x16x32_bf16(kf0, qf[0][0], sT[0][n], 0, 0, 0);
            sT[0][n] = __builtin_amdgcn_mfma_f32_16x16x32_bf16(kf1, qf[0][1], sT[0][n], 0, 0, 0);
            sT[1][n] = __builtin_amdgcn_mfma_f32_16x16x32_bf16(kf0, qf[1][0], sT[1][n], 0, 0, 0);
            sT[1][n] = __builtin_amdgcn_mfma_f32_16x16x32_bf16(kf1, qf[1][1], sT[1][n], 0, 0, 0);
        }
        __builtin_amdgcn_s_setprio(0);

        // P = exp(S*scale): in-register, pack straight into x16 A-fragments
        s16x4 pf[2][4];
        #pragma unroll
        for (int qh = 0; qh < 2; qh++)
            #pragma unroll
            for (int n = 0; n < 4; n++) {
                float e0 = __expf(sT[qh][n][0] * ATTN_SCALE);
                float e1 = __expf(sT[qh][n][1] * ATTN_SCALE);
                float e2 = __expf(sT[qh][n][2] * ATTN_SCALE);
                float e3 = __expf(sT[qh][n][3] * ATTN_SCALE);
                lsum[qh] += (e0 + e1) + (e2 + e3);
                unsigned int w0, w1;
                asm("v_cvt_pk_bf16_f32 %0, %1, %2" : "=v"(w0) : "v"(e0), "v"(e1));
                asm("v_cvt_pk_bf16_f32 %0, %1, %2" : "=v"(w1) : "v"(e2), "v"(e3));
                union { unsigned int u[2]; s16x4 v; } pu;
                pu.u[0] = w0; pu.u[1] = w1;
                pf[qh][n] = pu.v;
            }

        // O += P @ V  (x16 MFMAs; V frag = contiguous b64 from V^T)
        __builtin_amdgcn_s_setprio(1);
        #pragma unroll
        for (int nt = 0; nt < 4; nt++) {
            int drow = nt * 16 + low;
            #pragma unroll
            for (int n = 0; n < 4; n++) {
                s16x4 vf = *(const s16x4*)&Vt[drow * 68 + n * 16 + quad * 4];
                o[0][nt] = mfma16(pf[0][n], vf, o[0][nt]);
                o[1][nt] = mfma16(pf[1][n], vf, o[1][nt]);
            }
        }
        __builtin_amdgcn_s_setprio(0);
    }

    // full row-sums: combine the 4 quad-partials for each q=low
    #pragma unroll
    for (int qh = 0; qh < 2; qh++) {
        lsum[qh] += __shfl_xor(lsum[qh], 16, 64);
        lsum[qh] += __shfl_xor(lsum[qh], 32, 64);
    }
    #pragma unroll
    for (int qh = 0; qh < 2; qh++)
        #pragma unroll
        for (int r = 0; r < 4; r++) {
            float inv = 1.0f / __shfl(lsum[qh], quad * 4 + r, 64);
            int q = q0 + qh * 16 + quad * 4 + r;
            #pragma unroll
            for (int nt = 0; nt < 4; nt++)
                ctx[(rowbase + q) * EMBED + hoff + nt * 16 + low] =
                    f2bf(o[qh][nt][r] * inv);
        }
}

extern "C" void kernel_launch(void* const* d_in, const int* in_sizes, int n_in,
                              void* d_out, int out_size, void* d_ws, size_t ws_size,
                              hipStream_t stream) {
    const float* hidden = (const float*)d_in[0];
    const float* qkv_w  = (const float*)d_in[1];
    const float* qkv_b  = (const float*)d_in[2];
    const float* proj_w = (const float*)d_in[3];
    const float* proj_b = (const float*)d_in[4];
    float* out = (float*)d_out;        // fp32 output

    char* ws = (char*)d_ws;
    // hiddenBf dead after QKV GEMM; ctx written only by attn -> alias (stream-serialized).
    unsigned short* hiddenBf = (unsigned short*)ws;                      // 8192x768  bf16
    unsigned short* ctx      = (unsigned short*)ws;                      // aliases hiddenBf
    unsigned short* WqkvT    = (unsigned short*)(ws + 12582912);         // 2304x768  bf16
    unsigned short* WprojT   = (unsigned short*)(ws + 16121856);         // 768x768   bf16
    unsigned short* mixed    = (unsigned short*)(ws + 17301504);         // 8192x2304 bf16

    prep_k<<<dim3(3648), 256, 0, stream>>>(qkv_w, WqkvT, proj_w, WprojT, hidden, hiddenBf);
    gemm128<0><<<dim3(ROWS / 128, QKVN / 128), 256, 0, stream>>>(
        hiddenBf, WqkvT, qkv_b, mixed, ROWS, QKVN, EMBED);
    attn_k<<<dim3(96 * 8), 256, 0, stream>>>(mixed, ctx);
    gemm128<1><<<dim3(ROWS / 128, EMBED / 128), 256, 0, stream>>>(
        ctx, WprojT, proj_b, out, ROWS, EMBED, EMBED);
}

// Round 10
// 190.401 us; speedup vs baseline: 1.0608x; 1.0096x over previous
//
#include <hip/hip_runtime.h>

#define EMBED 768
#define NHEAD 12
#define HDIM 64
#define BATCH 8
#define SEQ 1024
#define ROWS (BATCH*SEQ)      // 8192
#define QKVN (3*EMBED)        // 2304
#define ATTN_SCALE 0.125f     // 1/sqrt(64)

typedef short s16x8 __attribute__((ext_vector_type(8)));
typedef short s16x4 __attribute__((ext_vector_type(4)));
typedef float f32x4 __attribute__((ext_vector_type(4)));

__device__ __forceinline__ float bf2f(unsigned short u) {
    union { unsigned int i; float f; } v; v.i = ((unsigned int)u) << 16; return v.f;
}
__device__ __forceinline__ unsigned short f2bf(float f) {
    unsigned int i = __builtin_bit_cast(unsigned int, f);
    i += 0x7FFFu + ((i >> 16) & 1u);   // RNE; finite values only
    return (unsigned short)(i >> 16);
}

// async global->LDS, 16 bytes per lane; LDS dest = wave-uniform base + lane*16
__device__ __forceinline__ void async16(short* lds, const unsigned short* g) {
    __builtin_amdgcn_global_load_lds(
        (const __attribute__((address_space(1))) unsigned int*)g,
        (__attribute__((address_space(3))) unsigned int*)lds,
        16, 0, 0);
}

__device__ __forceinline__ f32x4 mfma16(s16x4 a, s16x4 b, f32x4 c) {
#if __has_builtin(__builtin_amdgcn_mfma_f32_16x16x16bf16_1k)
    return __builtin_amdgcn_mfma_f32_16x16x16bf16_1k(a, b, c, 0, 0, 0);
#else
    asm volatile("v_mfma_f32_16x16x16_bf16 %0, %1, %2, %0" : "+v"(c) : "v"(a), "v"(b));
    return c;
#endif
}

// Fused prep.
// blk [0,432):   qkv_w fp32[768][2304] -> bf16 [2304][768]  (64x64 LDS tile transpose)
// blk [432,576): proj_w fp32[768][768] -> bf16 [768][768]
// blk [576,3648): hidden fp32 -> bf16 row-convert (8 elem/thread)
__global__ __launch_bounds__(256) void prep_k(
    const float* __restrict__ qkv_w, unsigned short* __restrict__ WqkvT,
    const float* __restrict__ proj_w, unsigned short* __restrict__ WprojT,
    const float* __restrict__ hidden, unsigned short* __restrict__ hiddenBf)
{
    __shared__ float tile[64][65];
    int blk = blockIdx.x;
    int t = threadIdx.x;
    if (blk < 576) {
        const float* in; unsigned short* outp; int K, N, tx, ty;
        if (blk < 432) { in = qkv_w; outp = WqkvT; K = EMBED; N = QKVN; tx = blk % 36; ty = blk / 36; }
        else { int b2 = blk - 432; in = proj_w; outp = WprojT; K = EMBED; N = EMBED; tx = b2 % 12; ty = b2 / 12; }
        int n0 = tx * 64, k0 = ty * 64;
        int c = t & 63, r0 = t >> 6;
        #pragma unroll
        for (int i = 0; i < 16; i++) {
            int r = r0 * 16 + i;
            tile[r][c] = in[(long long)(k0 + r) * N + n0 + c];   // coalesced 256B/row-group
        }
        __syncthreads();
        #pragma unroll
        for (int i = 0; i < 16; i++) {
            int nr = r0 * 16 + i;
            outp[(long long)(n0 + nr) * K + k0 + c] = f2bf(tile[c][nr]); // coalesced writes
        }
    } else {
        int tid = (blk - 576) * 256 + t;
        int base = tid * 8;
        float4 f0 = *(const float4*)&hidden[base];
        float4 f1 = *(const float4*)&hidden[base + 4];
        s16x8 a;
        a[0] = (short)f2bf(f0.x); a[1] = (short)f2bf(f0.y);
        a[2] = (short)f2bf(f0.z); a[3] = (short)f2bf(f0.w);
        a[4] = (short)f2bf(f1.x); a[5] = (short)f2bf(f1.y);
        a[6] = (short)f2bf(f1.z); a[7] = (short)f2bf(f1.w);
        *(s16x8*)&hiddenBf[base] = a;
    }
}

// m97-class GEMM + 2-phase double-buffer (PROVEN round 9, byte-identical):
// C = A @ Bt^T + bias. tile 128x128, BK=32, 4 waves.
// XCD slab swizzle; stage(next) before compute(cur); one barrier per K-step.
template <int OUT_F32>
__global__ __launch_bounds__(256) void gemm128(
    const unsigned short* __restrict__ A,
    const unsigned short* __restrict__ Bt,
    const float* __restrict__ bias,
    void* __restrict__ Cv,
    int M, int N, int K)
{
    __shared__ short As[2][128 * 32];
    __shared__ short Bs[2][128 * 32];
    int t = threadIdx.x, lane = t & 63, w = t >> 6;
    int quad = lane >> 4, low = lane & 15;
    // orig = (local<<3)|xcd ; (bx,by) = (xcd*8+(local&7), local>>3) — bijective.
    int orig = blockIdx.y * gridDim.x + blockIdx.x;
    int xcd = orig & 7;
    int local = orig >> 3;
    int bx = xcd * 8 + (local & 7);
    int by = local >> 3;
    int m0 = bx * 128, n0 = by * 128;
    int wm = (w & 1) * 64, wn = (w >> 1) * 64;

    int ci0 = w * 128 + lane;
    int r0 = ci0 >> 2, c0 = (ci0 & 3) ^ ((r0 >> 1) & 3);
    int ci1 = ci0 + 64;
    int r1 = ci1 >> 2, c1 = (ci1 & 3) ^ ((r1 >> 1) & 3);
    const unsigned short* pa0 = A + (long long)(m0 + r0) * K + c0 * 8;
    const unsigned short* pa1 = A + (long long)(m0 + r1) * K + c1 * 8;
    const unsigned short* pb0 = Bt + (long long)(n0 + r0) * K + c0 * 8;
    const unsigned short* pb1 = Bt + (long long)(n0 + r1) * K + c1 * 8;
    int lo0 = (w * 128) * 8;        // this wave's first chunk group (short offset)
    int lo1 = (w * 128 + 64) * 8;   // second chunk group

    // prologue: stage K-step 0 into buffer 0
    async16(&As[0][lo0], pa0);
    async16(&As[0][lo1], pa1);
    async16(&Bs[0][lo0], pb0);
    async16(&Bs[0][lo1], pb1);
    __syncthreads();

    f32x4 acc[4][4] = {};
    int cur = 0;
    for (int k0 = 0; k0 < K; k0 += 32) {
        int nxt = cur ^ 1;
        // stage next K-step into the other buffer (issued before compute;
        // lands by the barrier below, latency hidden under ds_read+MFMA)
        if (k0 + 32 < K) {
            async16(&As[nxt][lo0], pa0 + k0 + 32);
            async16(&As[nxt][lo1], pa1 + k0 + 32);
            async16(&Bs[nxt][lo0], pb0 + k0 + 32);
            async16(&Bs[nxt][lo1], pb1 + k0 + 32);
        }
        const short* as = As[cur];
        const short* bs = Bs[cur];
        s16x8 af[4], bfr[4];
        #pragma unroll
        for (int i = 0; i < 4; i++) {
            int ra = wm + i * 16 + low;
            af[i] = *(const s16x8*)&as[ra * 32 + ((quad ^ ((ra >> 1) & 3)) * 8)];
            int rb = wn + i * 16 + low;
            bfr[i] = *(const s16x8*)&bs[rb * 32 + ((quad ^ ((rb >> 1) & 3)) * 8)];
        }
        #pragma unroll
        for (int i = 0; i < 4; i++)
            #pragma unroll
            for (int j = 0; j < 4; j++)
                acc[i][j] = __builtin_amdgcn_mfma_f32_16x16x32_bf16(af[i], bfr[j], acc[i][j], 0, 0, 0);
        __syncthreads();   // reads of cur done (lgkm), stage of nxt landed (vmcnt)
        cur = nxt;
    }
    #pragma unroll
    for (int i = 0; i < 4; i++)
        #pragma unroll
        for (int j = 0; j < 4; j++)
            #pragma unroll
            for (int r = 0; r < 4; r++) {
                int m = m0 + wm + i * 16 + quad * 4 + r;
                int n = n0 + wn + j * 16 + low;
                float v = acc[i][j][r] + bias[n];
                if (OUT_F32) ((float*)Cv)[(long long)m * N + n] = v;
                else ((unsigned short*)Cv)[(long long)m * N + n] = f2bf(v);
            }
}

// MFMA flash attention v5: round-1 PROVEN inner tile code + 2-gang KV split.
// 512 threads = 2 gangs x 4 waves. Gang g processes kv [g*512, g*512+512) for
// the SAME 128 q-rows, with private K/V LDS buffers; inner tile code is
// byte-identical to the proven v4 kernel (expf softmax, swapped QK^T, in-reg P).
// No-max softmax => cross-gang combine is PURE ADDITION: o += o', lsum += lsum'
// (gang1 dumps to LDS overlaid on dead staging buffers; gang0 adds+normalizes).
// Waves/SIMD 3 -> 6 at constant VGPR: hides the ~2800cy per-tile chain that
// capped v4 at 27% MfmaUtil / 45% VALUBusy / 27% occupancy.
__global__ __launch_bounds__(512) void attn_k(
    const unsigned short* __restrict__ mixed,  // [8192][2304] : Q|K|V per row (bf16)
    unsigned short* __restrict__ ctx)          // [8192][768]
{
    // per gang: Ks 64*64*2B = 8192, Vt 64*68*2B = 8704 -> 16896B; 2 gangs 33792B.
    // epilogue overlay: xo 2048*f32x4 = 32768B + xl 512*f32 = 2048B -> 34816B.
    __shared__ __align__(16) char smem[34816];
    int blk = blockIdx.x;
    int bh = blk % 96;                 // XCD-grouped: 96 == 0 (mod 8)
    int qc = blk / 96;
    int b = bh / NHEAD, h = bh - b * NHEAD;
    int t = threadIdx.x;
    int tl = t & 255;                  // intra-gang thread id
    int lane = t & 63, w = t >> 6;     // w in 0..7
    int wq = w & 3, gang = w >> 2;
    int quad = lane >> 4, low = lane & 15;
    long long rowbase = (long long)b * SEQ;
    int q0 = qc * 128 + wq * 32;
    int hoff = h * HDIM;

    short* Ks = (short*)(smem + gang * 16896);        // K tile [kv][d], chunk-XOR swizzled
    short* Vt = (short*)(smem + gang * 16896 + 8192); // V^T tile [d][kv], kv padded ->68

    // Q fragments (B-operand of swapped QK^T; layout identical to A-frag): [qh][dhalf]
    s16x8 qf[2][2];
    #pragma unroll
    for (int qh = 0; qh < 2; qh++) {
        long long r = (rowbase + q0 + qh * 16 + low) * QKVN + hoff;
        qf[qh][0] = *(const s16x8*)&mixed[r + quad * 8];
        qf[qh][1] = *(const s16x8*)&mixed[r + 32 + quad * 8];
    }

    // K staging (per gang): slot = wq*128 + lane (+64); row = slot>>3, chunk = slot&7.
    // LDS phys chunk c of row r holds global d-chunk (c ^ (r&7)); read applies same XOR.
    int s0 = wq * 128 + lane;
    int kr0 = s0 >> 3, kc0 = s0 & 7;
    int kg = kc0 ^ (kr0 & 7);          // (kr0+8)&7 == kr0&7, so same for both slots
    const unsigned short* pk0 = mixed + (rowbase + kr0) * QKVN + EMBED + hoff + kg * 8;
    const unsigned short* pk1 = mixed + (rowbase + kr0 + 8) * QKVN + EMBED + hoff + kg * 8;
    short* lk0 = Ks + (wq * 128) * 8;
    short* lk1 = Ks + (wq * 128 + 64) * 8;

    // V staging (per gang): thread owns d = dblk*4..+3, kv rows rq*4..+3
    int dblk = tl & 15, rq = tl >> 4;
    const unsigned short* pv = mixed + (rowbase + rq * 4) * QKVN + 2 * EMBED + hoff + dblk * 4;

    f32x4 o[2][4] = {};
    float lsum[2] = {0.f, 0.f};

    int kvbase = gang * 512;           // gang's KV half
    for (int it = 0; it < 8; it++) {
        long long koff = (long long)(kvbase + it * 64) * QKVN;
        __syncthreads();
        async16(lk0, pk0 + koff);
        async16(lk1, pk1 + koff);
        s16x4 v0 = *(const s16x4*)&pv[koff];
        s16x4 v1 = *(const s16x4*)&pv[koff + QKVN];
        s16x4 v2 = *(const s16x4*)&pv[koff + 2 * QKVN];
        s16x4 v3 = *(const s16x4*)&pv[koff + 3 * QKVN];
        #pragma unroll
        for (int k = 0; k < 4; k++) {
            s16x4 wv;
            wv[0] = v0[k]; wv[1] = v1[k]; wv[2] = v2[k]; wv[3] = v3[k];
            *(s16x4*)&Vt[(dblk * 4 + k) * 68 + rq * 4] = wv;
        }
        __syncthreads();

        // S^T: per kv-16 block n, sT[qh][n][r] = S[q0+qh*16+low][kv...]
        f32x4 sT[2][4] = {};
        __builtin_amdgcn_s_setprio(1);
        #pragma unroll
        for (int n = 0; n < 4; n++) {
            int rr = n * 16 + low;
            int key = low & 7;
            s16x8 kf0 = *(const s16x8*)&Ks[rr * 64 + ((quad ^ key) * 8)];
            s16x8 kf1 = *(const s16x8*)&Ks[rr * 64 + (((quad + 4) ^ key) * 8)];
            sT[0][n] = __builtin_amdgcn_mfma_f32_16x16x32_bf16(kf0, qf[0][0], sT[0][n], 0, 0, 0);
            sT[0][n] = __builtin_amdgcn_mfma_f32_16x16x32_bf16(kf1, qf[0][1], sT[0][n], 0, 0, 0);
            sT[1][n] = __builtin_amdgcn_mfma_f32_16x16x32_bf16(kf0, qf[1][0], sT[1][n], 0, 0, 0);
            sT[1][n] = __builtin_amdgcn_mfma_f32_16x16x32_bf16(kf1, qf[1][1], sT[1][n], 0, 0, 0);
        }
        __builtin_amdgcn_s_setprio(0);

        // P = exp(S*scale): in-register, pack straight into x16 A-fragments
        s16x4 pf[2][4];
        #pragma unroll
        for (int qh = 0; qh < 2; qh++)
            #pragma unroll
            for (int n = 0; n < 4; n++) {
                float e0 = __expf(sT[qh][n][0] * ATTN_SCALE);
                float e1 = __expf(sT[qh][n][1] * ATTN_SCALE);
                float e2 = __expf(sT[qh][n][2] * ATTN_SCALE);
                float e3 = __expf(sT[qh][n][3] * ATTN_SCALE);
                lsum[qh] += (e0 + e1) + (e2 + e3);
                unsigned int w0, w1;
                asm("v_cvt_pk_bf16_f32 %0, %1, %2" : "=v"(w0) : "v"(e0), "v"(e1));
                asm("v_cvt_pk_bf16_f32 %0, %1, %2" : "=v"(w1) : "v"(e2), "v"(e3));
                union { unsigned int u[2]; s16x4 v; } pu;
                pu.u[0] = w0; pu.u[1] = w1;
                pf[qh][n] = pu.v;
            }

        // O += P @ V  (x16 MFMAs; V frag = contiguous b64 from V^T)
        __builtin_amdgcn_s_setprio(1);
        #pragma unroll
        for (int nt = 0; nt < 4; nt++) {
            int drow = nt * 16 + low;
            #pragma unroll
            for (int n = 0; n < 4; n++) {
                s16x4 vf = *(const s16x4*)&Vt[drow * 68 + n * 16 + quad * 4];
                o[0][nt] = mfma16(pf[0][n], vf, o[0][nt]);
                o[1][nt] = mfma16(pf[1][n], vf, o[1][nt]);
            }
        }
        __builtin_amdgcn_s_setprio(0);
    }

    // full row-sums within gang: combine the 4 quad-partials for each q=low
    #pragma unroll
    for (int qh = 0; qh < 2; qh++) {
        lsum[qh] += __shfl_xor(lsum[qh], 16, 64);
        lsum[qh] += __shfl_xor(lsum[qh], 32, 64);
    }

    // cross-gang combine (no-max softmax => pure addition), overlaid on staging LDS
    f32x4* xo = (f32x4*)smem;                 // [wq][qh][nt][lane] = 2048 x f32x4
    float*  xl = (float*)(smem + 32768);      // [wq][qh][lane]    = 512 x f32
    __syncthreads();                          // all staging reads done before overwrite
    if (gang == 1) {
        #pragma unroll
        for (int qh = 0; qh < 2; qh++) {
            #pragma unroll
            for (int nt = 0; nt < 4; nt++)
                xo[((wq * 2 + qh) * 4 + nt) * 64 + lane] = o[qh][nt];
            xl[(wq * 2 + qh) * 64 + lane] = lsum[qh];
        }
    }
    __syncthreads();
    if (gang == 0) {
        #pragma unroll
        for (int qh = 0; qh < 2; qh++) {
            #pragma unroll
            for (int nt = 0; nt < 4; nt++)
                o[qh][nt] += xo[((wq * 2 + qh) * 4 + nt) * 64 + lane];
            lsum[qh] += xl[(wq * 2 + qh) * 64 + lane];
        }
        #pragma unroll
        for (int qh = 0; qh < 2; qh++)
            #pragma unroll
            for (int r = 0; r < 4; r++) {
                float inv = 1.0f / __shfl(lsum[qh], quad * 4 + r, 64);
                int q = q0 + qh * 16 + quad * 4 + r;
                #pragma unroll
                for (int nt = 0; nt < 4; nt++)
                    ctx[(rowbase + q) * EMBED + hoff + nt * 16 + low] =
                        f2bf(o[qh][nt][r] * inv);
            }
    }
}

extern "C" void kernel_launch(void* const* d_in, const int* in_sizes, int n_in,
                              void* d_out, int out_size, void* d_ws, size_t ws_size,
                              hipStream_t stream) {
    const float* hidden = (const float*)d_in[0];
    const float* qkv_w  = (const float*)d_in[1];
    const float* qkv_b  = (const float*)d_in[2];
    const float* proj_w = (const float*)d_in[3];
    const float* proj_b = (const float*)d_in[4];
    float* out = (float*)d_out;        // fp32 output

    char* ws = (char*)d_ws;
    // hiddenBf dead after QKV GEMM; ctx written only by attn -> alias (stream-serialized).
    unsigned short* hiddenBf = (unsigned short*)ws;                      // 8192x768  bf16
    unsigned short* ctx      = (unsigned short*)ws;                      // aliases hiddenBf
    unsigned short* WqkvT    = (unsigned short*)(ws + 12582912);         // 2304x768  bf16
    unsigned short* WprojT   = (unsigned short*)(ws + 16121856);         // 768x768   bf16
    unsigned short* mixed    = (unsigned short*)(ws + 17301504);         // 8192x2304 bf16

    prep_k<<<dim3(3648), 256, 0, stream>>>(qkv_w, WqkvT, proj_w, WprojT, hidden, hiddenBf);
    gemm128<0><<<dim3(ROWS / 128, QKVN / 128), 256, 0, stream>>>(
        hiddenBf, WqkvT, qkv_b, mixed, ROWS, QKVN, EMBED);
    attn_k<<<dim3(96 * 8), 512, 0, stream>>>(mixed, ctx);
    gemm128<1><<<dim3(ROWS / 128, EMBED / 128), 256, 0, stream>>>(
        ctx, WprojT, proj_b, out, ROWS, EMBED, EMBED);
}